// Round 1
// baseline (44.005 us; speedup 1.0000x reference)
//
#include <hip/hip_runtime.h>

// Length regulator:
//   out[b, m, :] = x[b, searchsorted_right(cum(duration[b]), m), :]  for m < mel_len[b]
//   out[b, m, :] = 0                                                 otherwise
//   mel_len[b]   = sum_t duration[b, t]   (stored as float in d_out tail)
//
// Fixed problem geometry (from setup_inputs): B=32, T=512, D=384, max_len=3584.
// D and max_len are re-derived from in_sizes/out_size for safety.

#define LR_B 32
#define LR_T 512

// ---------------------------------------------------------------------------
// Kernel 1: per-batch inclusive scan of duration -> cum, and mel_len output.
// One block per batch, T threads (512 = 8 waves), LDS Hillis-Steele scan.
// ---------------------------------------------------------------------------
__global__ void lr_scan_kernel(const int* __restrict__ dur,
                               int* __restrict__ cum,
                               float* __restrict__ mel_out,
                               int T) {
    __shared__ int s[LR_T];
    const int b = blockIdx.x;
    const int t = threadIdx.x;
    s[t] = dur[b * T + t];
    __syncthreads();
    #pragma unroll
    for (int off = 1; off < LR_T; off <<= 1) {
        int add = (t >= off) ? s[t - off] : 0;
        __syncthreads();
        s[t] += add;
        __syncthreads();
    }
    cum[b * T + t] = s[t];
    if (t == T - 1) {
        mel_out[b] = (float)s[t];   // mel_len as float (exact, values << 2^24)
    }
}

// ---------------------------------------------------------------------------
// Kernel 2: per output frame, binary search cum for the source phoneme index.
// idx = first t with cum[t] > m (searchsorted side='right'), clipped to T-1;
// -1 sentinel marks padding frames (m >= mel_len).
// cum slice per batch is 2 KB -> L1-resident across the 3584 searches.
// ---------------------------------------------------------------------------
__global__ void lr_idx_kernel(const int* __restrict__ cum,
                              int* __restrict__ idx,
                              int T, int max_len) {
    const int b = blockIdx.y;
    const int m = blockIdx.x * blockDim.x + threadIdx.x;
    if (m >= max_len) return;
    const int* __restrict__ c = cum + b * T;
    const int total = c[T - 1];
    int r = -1;
    if (m < total) {
        int lo = 0, hi = T;
        while (lo < hi) {
            int mid = (lo + hi) >> 1;
            if (c[mid] <= m) lo = mid + 1; else hi = mid;
        }
        r = (lo < T) ? lo : (T - 1);
    }
    idx[b * max_len + m] = r;
}

// ---------------------------------------------------------------------------
// Kernel 3: gather-copy. One thread per float4 of output.
// Consecutive threads -> consecutive float4 within a frame -> fully coalesced
// 16 B/lane loads and stores. Padding frames store zeros (d_out is poisoned).
// ---------------------------------------------------------------------------
__global__ void lr_copy_kernel(const float4* __restrict__ x4,
                               const int* __restrict__ idx,
                               float4* __restrict__ out4,
                               int T, int max_len, int D4) {
    const int b = blockIdx.y;
    const int e = blockIdx.x * blockDim.x + threadIdx.x;  // < max_len*D4 = 344064
    const int tot = max_len * D4;
    if (e >= tot) return;
    const int m  = e / D4;          // magic-multiply division (D4 = 96)
    const int d4 = e - m * D4;
    const int id = idx[b * max_len + m];
    float4 v = make_float4(0.f, 0.f, 0.f, 0.f);
    if (id >= 0) {
        v = x4[((long)b * T + id) * D4 + d4];
    }
    out4[((long)b * max_len + m) * D4 + d4] = v;
}

extern "C" void kernel_launch(void* const* d_in, const int* in_sizes, int n_in,
                              void* d_out, int out_size, void* d_ws, size_t ws_size,
                              hipStream_t stream) {
    const float* x   = (const float*)d_in[0];
    const int*   dur = (const int*)d_in[1];
    // d_in[2] = max_len scalar on device; geometry re-derived on host instead.

    const int B = LR_B;
    const int T = LR_T;
    const int D = in_sizes[0] / in_sizes[1];            // 384
    const int max_len = (out_size / B - 1) / D;         // 3584
    const int D4 = D / 4;                               // 96

    float* out     = (float*)d_out;
    float* mel_out = out + (size_t)B * max_len * D;     // last B floats

    // Workspace layout: [cum: B*T ints][idx: B*max_len ints]
    int* cum = (int*)d_ws;
    int* idx = cum + (size_t)B * T;

    // 1) scan durations
    lr_scan_kernel<<<B, T, 0, stream>>>(dur, cum, mel_out, T);

    // 2) frame -> phoneme index
    {
        dim3 block(256, 1, 1);
        dim3 grid((max_len + 255) / 256, B, 1);
        lr_idx_kernel<<<grid, block, 0, stream>>>(cum, idx, T, max_len);
    }

    // 3) gather copy (one thread per float4)
    {
        const int tot = max_len * D4;                   // 344064 per batch
        dim3 block(256, 1, 1);
        dim3 grid((tot + 255) / 256, B, 1);
        lr_copy_kernel<<<grid, block, 0, stream>>>(
            (const float4*)x, idx, (float4*)d_out, T, max_len, D4);
    }
}

// Round 2
// 37.993 us; speedup vs baseline: 1.1582x; 1.1582x over previous
//
#include <hip/hip_runtime.h>

// Length regulator:
//   out[b, m, :] = x[b, searchsorted_right(cum(duration[b]), m), :]  for m < mel_len[b]
//   out[b, m, :] = 0                                                 otherwise
//   mel_len[b]   = sum_t duration[b, t]   (stored as float in d_out tail)
//
// Geometry (from setup_inputs): B=32, T=512, D=384, max_len=3584.
// D / max_len re-derived from in_sizes/out_size; fast path assumes D4==96.

#define LR_B 32
#define LR_T 512

// ---------------------------------------------------------------------------
// Kernel 1 (fused): per-batch LDS scan of duration -> cum, mel_len output,
// and per-frame binary search against the LDS cum -> idx array.
// One block per batch, 512 threads; each thread then covers max_len/512
// frames. No global round-trip for cum; one fewer launch in the graph.
// ---------------------------------------------------------------------------
__global__ void lr_scan_idx_kernel(const int* __restrict__ dur,
                                   int* __restrict__ idx,
                                   float* __restrict__ mel_out,
                                   int T, int max_len) {
    __shared__ int s[LR_T];
    const int b = blockIdx.x;
    const int t = threadIdx.x;
    s[t] = dur[b * T + t];
    __syncthreads();
    #pragma unroll
    for (int off = 1; off < LR_T; off <<= 1) {
        int add = (t >= off) ? s[t - off] : 0;
        __syncthreads();
        s[t] += add;
        __syncthreads();
    }
    const int total = s[T - 1];
    if (t == 0) {
        mel_out[b] = (float)total;   // mel_len as float (exact, values << 2^24)
    }
    int* __restrict__ idxb = idx + b * max_len;
    for (int m = t; m < max_len; m += LR_T) {
        int r = -1;
        if (m < total) {
            int lo = 0, hi = T;
            while (lo < hi) {                 // searchsorted side='right'
                int mid = (lo + hi) >> 1;
                if (s[mid] <= m) lo = mid + 1; else hi = mid;
            }
            r = (lo < T) ? lo : (T - 1);
        }
        idxb[m] = r;                          // coalesced: consecutive t -> consecutive m
    }
}

// ---------------------------------------------------------------------------
// Kernel 2: gather-copy. Each thread handles 4 float4s, strided by 256 within
// a contiguous 1024-element span -> fully coalesced 16 B/lane loads+stores,
// 16 KB of stores per workgroup. tot = max_len*D4 = 344064 = 1024*336 exactly
// (no bounds check on the fast path). Padding frames store zeros (d_out is
// poisoned before timing, so every element must be written).
// ---------------------------------------------------------------------------
template <int D4C>
__global__ void lr_copy_kernel(const float4* __restrict__ x4,
                               const int* __restrict__ idx,
                               float4* __restrict__ out4,
                               int T, int max_len) {
    const int b = blockIdx.y;
    const int tot = max_len * D4C;
    const int base = blockIdx.x * 1024 + threadIdx.x;
    const int* __restrict__ idxb = idx + b * max_len;
    const float4* __restrict__ xb = x4 + (size_t)b * T * D4C;
    float4* __restrict__ ob = out4 + (size_t)b * tot;
    #pragma unroll
    for (int j = 0; j < 4; ++j) {
        const int e  = base + j * 256;
        const int m  = e / D4C;               // compile-time divisor -> magic-mul
        const int d4 = e - m * D4C;
        const int id = idxb[m];               // broadcast across ~96 lanes via L1
        float4 v = make_float4(0.f, 0.f, 0.f, 0.f);
        if (id >= 0) v = xb[id * D4C + d4];
        ob[e] = v;
    }
}

// Generic fallback (runtime D4, bounds-checked) in case geometry differs.
__global__ void lr_copy_generic(const float4* __restrict__ x4,
                                const int* __restrict__ idx,
                                float4* __restrict__ out4,
                                int T, int max_len, int D4) {
    const int b = blockIdx.y;
    const int tot = max_len * D4;
    const int e = blockIdx.x * blockDim.x + threadIdx.x;
    if (e >= tot) return;
    const int m  = e / D4;
    const int d4 = e - m * D4;
    const int id = idx[b * max_len + m];
    float4 v = make_float4(0.f, 0.f, 0.f, 0.f);
    if (id >= 0) v = x4[((size_t)b * T + id) * D4 + d4];
    out4[(size_t)b * tot + e] = v;
}

extern "C" void kernel_launch(void* const* d_in, const int* in_sizes, int n_in,
                              void* d_out, int out_size, void* d_ws, size_t ws_size,
                              hipStream_t stream) {
    const float* x   = (const float*)d_in[0];
    const int*   dur = (const int*)d_in[1];

    const int B = LR_B;
    const int T = LR_T;
    const int D = in_sizes[0] / in_sizes[1];            // 384
    const int max_len = (out_size / B - 1) / D;         // 3584
    const int D4 = D / 4;                               // 96

    float* out     = (float*)d_out;
    float* mel_out = out + (size_t)B * max_len * D;     // last B floats

    int* idx = (int*)d_ws;                              // B*max_len ints

    // 1) fused scan + frame->phoneme index
    lr_scan_idx_kernel<<<B, T, 0, stream>>>(dur, idx, mel_out, T, max_len);

    // 2) gather copy
    const int tot = max_len * D4;                       // 344064 per batch
    if (D4 == 96 && (tot % 1024) == 0) {
        dim3 grid(tot / 1024, B, 1);                    // 336 x 32
        lr_copy_kernel<96><<<grid, dim3(256, 1, 1), 0, stream>>>(
            (const float4*)x, idx, (float4*)d_out, T, max_len);
    } else {
        dim3 grid((tot + 255) / 256, B, 1);
        lr_copy_generic<<<grid, dim3(256, 1, 1), 0, stream>>>(
            (const float4*)x, idx, (float4*)d_out, T, max_len, D4);
    }
}

// Round 4
// 35.155 us; speedup vs baseline: 1.2517x; 1.0807x over previous
//
#include <hip/hip_runtime.h>

// Length regulator (fully fused, single kernel):
//   out[b, m, :] = x[b, searchsorted_right(cum(duration[b]), m), :]  for m < mel_len[b]
//   out[b, m, :] = 0                                                 otherwise
//   mel_len[b]   = sum_t duration[b, t]   (stored as float in d_out tail)
//
// Geometry (from setup_inputs): B=32, T=512, D=384, max_len=3584.
// Fast path assumes T==512, D4==96, tot%1024==0; generic 2-kernel fallback kept.
//
// Fusion rationale (R3): the separate 32-block scan kernel was pure serialized
// latency (~6-9us). Each copy block instead redundantly scans its batch's 512
// durations in LDS (2KB, L2-hit) and binary-searches only its own ~12 frames.
//
// R4 fix: __builtin_nontemporal_store needs a native vector type, not HIP's
// float4 class -> use clang ext_vector_type(4).

#define LR_B 32
#define LR_T 512

typedef float f32x4 __attribute__((ext_vector_type(4)));

// ---------------------------------------------------------------------------
// Fused kernel: block = (frame-chunk, batch). 256 threads, 1024 float4s/block.
//  1. load 512 durations -> LDS, Hillis-Steele inclusive scan (2 elems/thread)
//  2. threads 0..NF-1 binary-search the block's NF (<=12) frames -> idx_s
//  3. unrolled x4 gather-copy, nontemporal streaming stores
// ---------------------------------------------------------------------------
template <int D4C>
__global__ __launch_bounds__(256) void lr_fused_kernel(
        const f32x4* __restrict__ x4,
        const int* __restrict__ dur,
        f32x4* __restrict__ out4,
        float* __restrict__ mel_out,
        int T, int max_len) {
    __shared__ int s[LR_T];
    __shared__ int idx_s[16];

    const int b  = blockIdx.y;
    const int bx = blockIdx.x;
    const int t  = threadIdx.x;

    // --- 1. scan of duration[b, :] (512 elems, 256 threads, 2 per thread) ---
    const int* __restrict__ db = dur + b * LR_T;
    s[t]       = db[t];
    s[t + 256] = db[t + 256];
    __syncthreads();
    #pragma unroll
    for (int off = 1; off < LR_T; off <<= 1) {
        const int p1 = t + 256;
        const int a0 = (t >= off) ? s[t - off] : 0;
        const int a1 = s[p1 - off];            // p1 >= 256 >= off always
        __syncthreads();
        s[t]  += a0;
        s[p1] += a1;
        __syncthreads();
    }
    const int total = s[LR_T - 1];

    if (bx == 0 && t == 0) {
        mel_out[b] = (float)total;             // exact: total <= 3584 << 2^24
    }

    // --- 2. per-block frame index cache ---
    const int e0 = bx * 1024;                  // first float4 element of block
    const int m0 = e0 / D4C;                   // first frame touched
    const int m1 = (e0 + 1023) / D4C;          // last frame touched
    const int NF = m1 - m0 + 1;                // <= 12 for D4C==96
    if (t < NF) {
        const int m = m0 + t;
        int r = -1;
        if (m < total) {
            int lo = 0, hi = T;
            while (lo < hi) {                  // searchsorted side='right'
                const int mid = (lo + hi) >> 1;
                if (s[mid] <= m) lo = mid + 1; else hi = mid;
            }
            r = (lo < T) ? lo : (T - 1);
        }
        idx_s[t] = r;
    }
    __syncthreads();

    // --- 3. gather-copy: 4 float4s per thread, coalesced, streaming stores ---
    const f32x4* __restrict__ xb = x4 + (size_t)b * T * D4C;
    f32x4* __restrict__ ob = out4 + (size_t)b * (size_t)max_len * D4C;
    #pragma unroll
    for (int j = 0; j < 4; ++j) {
        const int e  = e0 + j * 256 + t;
        const int m  = e / D4C;                // compile-time divisor -> magic-mul
        const int d4 = e - m * D4C;
        const int id = idx_s[m - m0];          // LDS broadcast across lanes
        f32x4 v = (f32x4){0.f, 0.f, 0.f, 0.f};
        if (id >= 0) v = xb[id * D4C + d4];
        __builtin_nontemporal_store(v, &ob[e]);
    }
}

// ---------------------------------------------------------------------------
// Generic fallback path (runtime geometry), two kernels as in R2.
// ---------------------------------------------------------------------------
__global__ void lr_scan_idx_kernel(const int* __restrict__ dur,
                                   int* __restrict__ idx,
                                   float* __restrict__ mel_out,
                                   int T, int max_len) {
    __shared__ int s[LR_T];
    const int b = blockIdx.x;
    const int t = threadIdx.x;
    s[t] = dur[b * T + t];
    __syncthreads();
    #pragma unroll
    for (int off = 1; off < LR_T; off <<= 1) {
        int add = (t >= off) ? s[t - off] : 0;
        __syncthreads();
        s[t] += add;
        __syncthreads();
    }
    const int total = s[T - 1];
    if (t == 0) mel_out[b] = (float)total;
    int* __restrict__ idxb = idx + b * max_len;
    for (int m = t; m < max_len; m += LR_T) {
        int r = -1;
        if (m < total) {
            int lo = 0, hi = T;
            while (lo < hi) {
                int mid = (lo + hi) >> 1;
                if (s[mid] <= m) lo = mid + 1; else hi = mid;
            }
            r = (lo < T) ? lo : (T - 1);
        }
        idxb[m] = r;
    }
}

__global__ void lr_copy_generic(const f32x4* __restrict__ x4,
                                const int* __restrict__ idx,
                                f32x4* __restrict__ out4,
                                int T, int max_len, int D4) {
    const int b = blockIdx.y;
    const int tot = max_len * D4;
    const int e = blockIdx.x * blockDim.x + threadIdx.x;
    if (e >= tot) return;
    const int m  = e / D4;
    const int d4 = e - m * D4;
    const int id = idx[b * max_len + m];
    f32x4 v = (f32x4){0.f, 0.f, 0.f, 0.f};
    if (id >= 0) v = x4[((size_t)b * T + id) * D4 + d4];
    out4[(size_t)b * tot + e] = v;
}

extern "C" void kernel_launch(void* const* d_in, const int* in_sizes, int n_in,
                              void* d_out, int out_size, void* d_ws, size_t ws_size,
                              hipStream_t stream) {
    const float* x   = (const float*)d_in[0];
    const int*   dur = (const int*)d_in[1];

    const int B = LR_B;
    const int T = in_sizes[1] / B;                      // 512
    const int D = in_sizes[0] / in_sizes[1];            // 384
    const int max_len = (out_size / B - 1) / D;         // 3584
    const int D4 = D / 4;                               // 96
    const int tot = max_len * D4;                       // 344064 per batch

    float* out     = (float*)d_out;
    float* mel_out = out + (size_t)B * max_len * D;     // last B floats

    if (T == LR_T && D4 == 96 && (tot % 1024) == 0) {
        dim3 grid(tot / 1024, B, 1);                    // 336 x 32 = 10752 blocks
        lr_fused_kernel<96><<<grid, dim3(256, 1, 1), 0, stream>>>(
            (const f32x4*)x, dur, (f32x4*)d_out, mel_out, T, max_len);
    } else {
        int* idx = (int*)d_ws;                          // B*max_len ints
        lr_scan_idx_kernel<<<B, T, 0, stream>>>(dur, idx, mel_out, T, max_len);
        dim3 grid((tot + 255) / 256, B, 1);
        lr_copy_generic<<<grid, dim3(256, 1, 1), 0, stream>>>(
            (const f32x4*)x, idx, (f32x4*)d_out, T, max_len, D4);
    }
}